// Round 7
// baseline (436.558 us; speedup 1.0000x reference)
//
#include <hip/hip_runtime.h>
#include <hip/hip_bf16.h>

#define DEVINL __device__ __forceinline__

typedef unsigned short u16;
typedef short v8s   __attribute__((ext_vector_type(8)));
typedef float v4f   __attribute__((ext_vector_type(4)));
typedef u16   v4u16 __attribute__((ext_vector_type(4)));
typedef short v4s16 __attribute__((ext_vector_type(4)));

constexpr int Bg      = 64;
constexpr int Nn      = 512;
constexpr int Vv      = 64;
constexpr int IND     = 128;
constexpr int Hd      = 256;
constexpr int OUTD    = 10;
constexpr int TOTAL_N = Bg * Nn;    // 32768
constexpr int NE      = Bg * 16384; // 1048576

DEVINL u16 f2bf(float f) {
    unsigned u = __float_as_uint(f);
    u += 0x7FFF + ((u >> 16) & 1);   // RNE
    return (u16)(u >> 16);
}
DEVINL float bf2f(u16 s) { return __uint_as_float(((unsigned)s) << 16); }

DEVINL void ld4f(const float* p, float o[4]) {
    float4 v = *(const float4*)p;
    o[0] = v.x; o[1] = v.y; o[2] = v.z; o[3] = v.w;
}
DEVINL void ld4f(const u16* p, float o[4]) {
    v4u16 v = *(const v4u16*)p;
    o[0] = bf2f(v[0]); o[1] = bf2f(v[1]); o[2] = bf2f(v[2]); o[3] = bf2f(v[3]);
}
DEVINL void stC(float* C, size_t idx, float v) { C[idx] = v; }
DEVINL void stC(u16* C, size_t idx, float v)   { C[idx] = f2bf(v); }

// ---------------- fused prep: weight transposes + b12 + zero cnt ----------------
struct WtArgs {
    const float* src[5];
    u16* dst[5];
    const float* b_emb;
    const float* W_gcn;
    float* b12;
    int* cnt;
};
__global__ __launch_bounds__(256) void k_prep(WtArgs a) {
    int bid = blockIdx.x;
    int t = threadIdx.x;
    if (bid >= 81) {
        a.cnt[(bid - 81) * 256 + t] = 0;
        return;
    }
    if (bid == 80) {
        float acc = 0.f;
        for (int k = 0; k < IND; k++) acc += a.b_emb[k] * a.W_gcn[(size_t)k * 256 + t];
        a.b12[t] = acc;
        return;
    }
    int mi = bid / 16, tile = bid % 16;
    int k0 = (tile & 3) * 64, n0 = (tile >> 2) * 64;
    const float* src = a.src[mi];
    u16* dst = a.dst[mi];
    __shared__ float T[64][65];
#pragma unroll
    for (int j = 0; j < 16; j++) {
        int idx = t + 256 * j;
        int r = idx >> 6, c = idx & 63;
        T[c][r] = src[(size_t)(k0 + r) * 256 + n0 + c];
    }
    __syncthreads();
#pragma unroll
    for (int j = 0; j < 16; j++) {
        int idx = t + 256 * j;
        int nr = idx >> 6, kc = idx & 63;
        dst[(size_t)(n0 + nr) * 256 + k0 + kc] = f2bf(T[nr][kc]);
    }
}

// ---------------- edge count ----------------
__global__ void k_count(const int* __restrict__ edst, int* __restrict__ cnt) {
    int e = blockIdx.x * blockDim.x + threadIdx.x;
    if (e < NE) atomicAdd(&cnt[edst[e]], 1);
}

// ---------------- exclusive scan over 32768 counts ----------------
__global__ __launch_bounds__(1024) void k_scan(const int* __restrict__ cnt,
                                               int* __restrict__ rowstart,
                                               int* __restrict__ cursor,
                                               float* __restrict__ dinv) {
    __shared__ int part[1024];
    int t = threadIdx.x;
    int base = t * 32;
    int local[32];
    int s = 0;
#pragma unroll
    for (int i = 0; i < 32; i++) { local[i] = cnt[base + i]; s += local[i]; }
    part[t] = s;
    __syncthreads();
    for (int off = 1; off < 1024; off <<= 1) {
        int v = (t >= off) ? part[t - off] : 0;
        __syncthreads();
        part[t] += v;
        __syncthreads();
    }
    int run = part[t] - s;
#pragma unroll
    for (int i = 0; i < 32; i++) {
        int idx = base + i;
        rowstart[idx] = run;
        cursor[idx]   = run;
        dinv[idx] = rsqrtf((float)(local[i] + 1));
        run += local[i];
    }
    if (t == 0) rowstart[TOTAL_N] = NE;
}

// ---------------- scatter edges into CSR (src only) ----------------
__global__ void k_scatter(const int* __restrict__ esrc, const int* __restrict__ edst,
                          int* __restrict__ cursor, int* __restrict__ csr_src) {
    int e = blockIdx.x * blockDim.x + threadIdx.x;
    if (e >= NE) return;
    int s = esrc[e], d = edst[e];
    int pos = atomicAdd(&cursor[d], 1);
    csr_src[pos] = s;
}

// ---------------- aggregate x: xa = A_norm@x + x/deg ; srow ----------------
// one wave per node; register+shfl edge broadcast, 8 gathers in flight.
__global__ __launch_bounds__(256) void k_aggx(const float2* __restrict__ x2,
                                              const int* __restrict__ rowstart,
                                              const int* __restrict__ csr_src,
                                              const float* __restrict__ dinv,
                                              float2* __restrict__ xa2,
                                              float* __restrict__ srow) {
    int tid = threadIdx.x;
    int lane = tid & 63, w = tid >> 6;
    // XCD swizzle: 8192 blocks; b>>3 in [0,1024)=2^10 -> XCD id in bits [10:12]
    int swb = ((blockIdx.x & 7) << 10) | (blockIdx.x >> 3);
    int node = swb * 4 + w;
    float di = dinv[node];
    float invdeg = di * di;
    float2 xv0 = x2[(size_t)node * 64 + lane];
    float ax = xv0.x * invdeg, ay = xv0.y * invdeg;
    float csum = 0.f;
    int rs0 = rowstart[node], rs1 = rowstart[node + 1];
    for (int base = rs0; base < rs1; base += 64) {
        int e = base + lane;
        int s = 0; float c = 0.f;
        if (e < rs1) { s = csr_src[e]; c = dinv[s] * di; csum += c; }
        int m = rs1 - base; if (m > 64) m = 64;
        for (int i = 0; i < m; i += 8) {   // overrun lanes have c=0 (i+u <= 63)
            int   ss[8]; float cc[8]; float2 vv[8];
#pragma unroll
            for (int u = 0; u < 8; u++) { ss[u] = __shfl(s, i + u); cc[u] = __shfl(c, i + u); }
#pragma unroll
            for (int u = 0; u < 8; u++) vv[u] = x2[(size_t)ss[u] * 64 + lane];
#pragma unroll
            for (int u = 0; u < 8; u++) { ax += vv[u].x * cc[u]; ay += vv[u].y * cc[u]; }
        }
    }
    float2 o; o.x = ax; o.y = ay;
    xa2[(size_t)node * 64 + lane] = o;
#pragma unroll
    for (int off = 32; off > 0; off >>= 1) csum += __shfl_xor(csum, off);
    if (lane == 0) srow[node] = invdeg + csum;
}

// ---------------- MFMA GEMM: C[M,256] = A[M,K] @ W[K,256] epilogues ------------
template <typename TA, typename TC>
__global__ __launch_bounds__(256) void k_mfma_gemm(const TA* __restrict__ A,
                                                   const u16* __restrict__ Wt,
                                                   const float* __restrict__ bias,
                                                   const float* __restrict__ srow,
                                                   const float* __restrict__ b12v,
                                                   TC* __restrict__ C,
                                                   int M, int K, int relu, int tstore) {
    constexpr int LDK = 88;
    __shared__ short As[128 * LDK];
    __shared__ short Bs[128 * LDK];
    int tid  = threadIdx.x;
    int row0 = blockIdx.y * 128, col0 = blockIdx.x * 128;
    int lane = tid & 63, wid = tid >> 6;
    int wm = (wid >> 1) * 64, wn = (wid & 1) * 64;
    int q = lane >> 4, r = lane & 15;
    v4f acc[4][4];
#pragma unroll
    for (int i = 0; i < 4; i++)
#pragma unroll
        for (int j = 0; j < 4; j++) acc[i][j] = (v4f){0.f, 0.f, 0.f, 0.f};
    int sm = tid >> 1, sk = (tid & 1) * 32;
    for (int k0 = 0; k0 < K; k0 += 64) {
        const TA* ap  = A  + (size_t)(row0 + sm) * K + k0 + sk;
        const u16* bp = Wt + (size_t)(col0 + sm) * K + k0 + sk;
        short* adst = &As[sm * LDK + sk];
        short* bdst = &Bs[sm * LDK + sk];
#pragma unroll
        for (int i = 0; i < 8; i++) {
            float o[4];
            ld4f(ap + 4 * i, o);
            v4s16 pa;
            pa[0] = (short)f2bf(o[0]); pa[1] = (short)f2bf(o[1]);
            pa[2] = (short)f2bf(o[2]); pa[3] = (short)f2bf(o[3]);
            *(v4s16*)(adst + 4 * i) = pa;
            *(v4u16*)(bdst + 4 * i) = *(const v4u16*)(bp + 4 * i);
        }
        __syncthreads();
#pragma unroll
        for (int ks = 0; ks < 64; ks += 32) {
            v8s af[4], bfr[4];
#pragma unroll
            for (int i = 0; i < 4; i++)
                af[i] = *(const v8s*)&As[(wm + i * 16 + r) * LDK + ks + q * 8];
#pragma unroll
            for (int j = 0; j < 4; j++)
                bfr[j] = *(const v8s*)&Bs[(wn + j * 16 + r) * LDK + ks + q * 8];
#pragma unroll
            for (int i = 0; i < 4; i++)
#pragma unroll
                for (int j = 0; j < 4; j++)
                    acc[i][j] = __builtin_amdgcn_mfma_f32_16x16x32_bf16(af[i], bfr[j], acc[i][j], 0, 0, 0);
        }
        __syncthreads();
    }
#pragma unroll
    for (int i = 0; i < 4; i++) {
#pragma unroll
        for (int j = 0; j < 4; j++) {
            int col = col0 + wn + j * 16 + r;
            float bcol = bias ? bias[col] : 0.f;
            float b12c = b12v ? b12v[col] : 0.f;
#pragma unroll
            for (int rg = 0; rg < 4; rg++) {
                int row = row0 + wm + i * 16 + q * 4 + rg;
                float v = acc[i][j][rg] + bcol;
                if (srow) v += srow[row] * b12c;
                if (relu) v = fmaxf(v, 0.f);
                if (tstore) stC(C, (size_t)col * M + row, v);
                else        stC(C, (size_t)row * 256 + col, v);
            }
        }
    }
}

// ---------------- fused per-graph tail: proto+att+vn+MLP+head ----------------
constexpr int LDV = 36;  // phase-3 n-stride (shorts)
constexpr int LDW = 264; // vnS h-stride (shorts), 528B rows
DEVINL v8s ld_frag36(const short* p) {
    v4s16 lo = *(const v4s16*)p;
    v4s16 hi = *(const v4s16*)(p + 4);
    v8s f;
    f[0] = lo[0]; f[1] = lo[1]; f[2] = lo[2]; f[3] = lo[3];
    f[4] = hi[0]; f[5] = hi[1]; f[6] = hi[2]; f[7] = hi[3];
    return f;
}
__global__ __launch_bounds__(256) void k_graph(const u16* __restrict__ t,
                                               const float* __restrict__ ew,
                                               const u16* __restrict__ g,
                                               const u16* __restrict__ wt_v1,
                                               const float* __restrict__ vb1,
                                               const u16* __restrict__ wt_v2,
                                               const float* __restrict__ vb2,
                                               const float* __restrict__ mW1,
                                               const float* __restrict__ mb1,
                                               const float* __restrict__ mW2,
                                               const float* __restrict__ mb2,
                                               float* __restrict__ out) {
    __shared__ float part[4][256];
    __shared__ float protos[256];
    __shared__ float red[256];
    __shared__ float scaleS[512];
    __shared__ short As[64 * LDV];
    __shared__ short Bs[256 * LDV];
    __shared__ short vnS[64 * LDW];
    __shared__ float gfS[256];
    __shared__ float zs[256];
    int b = blockIdx.x, tid = threadIdx.x;
    int lane = tid & 63, wv = tid >> 6;
    int q = lane >> 4, r = lane & 15;

    // ---- phase 1: proto = mean_n t ; pn ----
    {
        float s0 = 0, s1 = 0, s2 = 0, s3 = 0;
        for (int n = wv * 128; n < wv * 128 + 128; n++) {
            v4u16 tv = *(const v4u16*)&t[(size_t)(b * Nn + n) * Hd + lane * 4];
            s0 += bf2f(tv[0]); s1 += bf2f(tv[1]); s2 += bf2f(tv[2]); s3 += bf2f(tv[3]);
        }
        part[wv][lane * 4 + 0] = s0;
        part[wv][lane * 4 + 1] = s1;
        part[wv][lane * 4 + 2] = s2;
        part[wv][lane * 4 + 3] = s3;
    }
    __syncthreads();
    {
        float p = (part[0][tid] + part[1][tid] + part[2][tid] + part[3][tid]) * (1.f / (float)Nn);
        protos[tid] = p;
        red[tid] = p * p;
    }
    __syncthreads();
    for (int off = 128; off > 0; off >>= 1) {
        if (tid < off) red[tid] += red[tid + off];
        __syncthreads();
    }
    float pnb = fmaxf(sqrtf(red[0]), 1e-8f);

    // ---- phase 2: scale[n] ----
    {
        float4 pv4 = *(const float4*)&protos[lane * 4];
        for (int n = wv; n < Nn; n += 4) {
            int node = b * Nn + n;
            v4u16 tv4 = *(const v4u16*)&t[(size_t)node * Hd + lane * 4];
            float t0 = bf2f(tv4[0]), t1 = bf2f(tv4[1]), t2 = bf2f(tv4[2]), t3 = bf2f(tv4[3]);
            float dot = t0 * pv4.x + t1 * pv4.y + t2 * pv4.z + t3 * pv4.w;
            float sq  = t0 * t0 + t1 * t1 + t2 * t2 + t3 * t3;
            float wvv = ew[(size_t)node * Vv + lane];
#pragma unroll
            for (int off = 32; off > 0; off >>= 1) {
                dot += __shfl_xor(dot, off);
                sq  += __shfl_xor(sq, off);
                wvv += __shfl_xor(wvv, off);
            }
            if (lane == 0) {
                float tn  = fmaxf(sqrtf(sq), 1e-8f);
                float sim = dot / (tn * pnb);
                float att = 0.5f * (1.f + sim);
                float rs  = att * wvv;
                float den = (rs == 0.f) ? 1.f : rs;
                scaleS[n] = att / den;
            }
        }
    }
    __syncthreads();

    // ---- phase 3: vn = (ew*scale)^T @ g[b] ----
    int h0 = wv * 64;
    v4f acc[4][4];
#pragma unroll
    for (int i = 0; i < 4; i++)
#pragma unroll
        for (int j = 0; j < 4; j++) acc[i][j] = (v4f){0.f, 0.f, 0.f, 0.f};
    for (int k0 = 0; k0 < Nn; k0 += 32) {
#pragma unroll
        for (int p = 0; p < 8; p++) {
            int e = tid + 256 * p;
            int nl = e >> 6, v = e & 63;
            int n = b * Nn + k0 + nl;
            As[v * LDV + nl] = (short)f2bf(ew[(size_t)n * Vv + v] * scaleS[k0 + nl]);
        }
#pragma unroll
        for (int p = 0; p < 8; p++) {
            int e = tid + 256 * p;
            int h = e & 255, kgrp = e >> 8;
            int kl = kgrp * 4;
            v4s16 tmp;
#pragma unroll
            for (int c = 0; c < 4; c++)
                tmp[c] = (short)g[(size_t)(b * Nn + k0 + kl + c) * Hd + h];
            *(v4s16*)&Bs[h * LDV + kl] = tmp;
        }
        __syncthreads();
        v8s af[4], bfr[4];
#pragma unroll
        for (int i = 0; i < 4; i++)
            af[i] = ld_frag36(&As[(i * 16 + r) * LDV + q * 8]);
#pragma unroll
        for (int j = 0; j < 4; j++)
            bfr[j] = ld_frag36(&Bs[(h0 + j * 16 + r) * LDV + q * 8]);
#pragma unroll
        for (int i = 0; i < 4; i++)
#pragma unroll
            for (int j = 0; j < 4; j++)
                acc[i][j] = __builtin_amdgcn_mfma_f32_16x16x32_bf16(af[i], bfr[j], acc[i][j], 0, 0, 0);
        __syncthreads();
    }
    // vn -> vnS (bf16, [v][h] stride LDW)
#pragma unroll
    for (int i = 0; i < 4; i++)
#pragma unroll
        for (int j = 0; j < 4; j++) {
            int col = h0 + j * 16 + r;
#pragma unroll
            for (int rg = 0; rg < 4; rg++) {
                int v = i * 16 + q * 4 + rg;
                vnS[v * LDW + col] = (short)f2bf(acc[i][j][rg]);
            }
        }
    __syncthreads();

    // ---- phase 4: vtmp = relu(vn @ vW1 + vb1) (K=256, B from global wt_v1[n][k]) ----
#pragma unroll
    for (int i = 0; i < 4; i++)
#pragma unroll
        for (int j = 0; j < 4; j++) acc[i][j] = (v4f){0.f, 0.f, 0.f, 0.f};
    for (int ks = 0; ks < Hd; ks += 32) {
        v8s af[4], bfr[4];
#pragma unroll
        for (int i = 0; i < 4; i++)
            af[i] = *(const v8s*)&vnS[(i * 16 + r) * LDW + ks + q * 8];
#pragma unroll
        for (int j = 0; j < 4; j++)
            bfr[j] = *(const v8s*)&wt_v1[(size_t)(h0 + j * 16 + r) * Hd + ks + q * 8];
#pragma unroll
        for (int i = 0; i < 4; i++)
#pragma unroll
            for (int j = 0; j < 4; j++)
                acc[i][j] = __builtin_amdgcn_mfma_f32_16x16x32_bf16(af[i], bfr[j], acc[i][j], 0, 0, 0);
    }
    __syncthreads();   // all vnS reads done
#pragma unroll
    for (int i = 0; i < 4; i++)
#pragma unroll
        for (int j = 0; j < 4; j++) {
            int col = h0 + j * 16 + r;
            float bv = vb1[col];
#pragma unroll
            for (int rg = 0; rg < 4; rg++) {
                int v = i * 16 + q * 4 + rg;
                vnS[v * LDW + col] = (short)f2bf(fmaxf(acc[i][j][rg] + bv, 0.f));
            }
        }
    __syncthreads();

    // ---- phase 5: vn2 = vtmp @ vW2 + vb2 ; gf = mean_v + vb2 ----
#pragma unroll
    for (int i = 0; i < 4; i++)
#pragma unroll
        for (int j = 0; j < 4; j++) acc[i][j] = (v4f){0.f, 0.f, 0.f, 0.f};
    for (int ks = 0; ks < Hd; ks += 32) {
        v8s af[4], bfr[4];
#pragma unroll
        for (int i = 0; i < 4; i++)
            af[i] = *(const v8s*)&vnS[(i * 16 + r) * LDW + ks + q * 8];
#pragma unroll
        for (int j = 0; j < 4; j++)
            bfr[j] = *(const v8s*)&wt_v2[(size_t)(h0 + j * 16 + r) * Hd + ks + q * 8];
#pragma unroll
        for (int i = 0; i < 4; i++)
#pragma unroll
            for (int j = 0; j < 4; j++)
                acc[i][j] = __builtin_amdgcn_mfma_f32_16x16x32_bf16(af[i], bfr[j], acc[i][j], 0, 0, 0);
    }
#pragma unroll
    for (int j = 0; j < 4; j++) {
        int col = h0 + j * 16 + r;
        float sum = 0.f;
#pragma unroll
        for (int i = 0; i < 4; i++)
#pragma unroll
            for (int rg = 0; rg < 4; rg++) sum += acc[i][j][rg];
        sum += __shfl_xor(sum, 16);
        sum += __shfl_xor(sum, 32);
        if (lane < 16) gfS[col] = sum * (1.f / (float)Vv) + vb2[col];
    }
    __syncthreads();

    // ---- phase 6: head ----
    {
        float z = mb1[tid];
        for (int k = 0; k < Hd; k++) z += gfS[k] * mW1[k * Hd + tid];
        zs[tid] = fmaxf(z, 0.f);
    }
    __syncthreads();
    if (tid < OUTD) {
        float o = mb2[tid];
        for (int ch = 0; ch < Hd; ch++) o += zs[ch] * mW2[ch * OUTD + tid];
        out[b * OUTD + tid] = o;
    }
}

// =======================================================================
extern "C" void kernel_launch(void* const* d_in, const int* in_sizes, int n_in,
                              void* d_out, int out_size, void* d_ws, size_t ws_size,
                              hipStream_t stream) {
    const float* x     = (const float*)d_in[0];
    const int*   esrc  = (const int*)d_in[1];
    const int*   edst  = (const int*)d_in[2];
    const float* W_emb = (const float*)d_in[3];
    const float* b_emb = (const float*)d_in[4];
    const float* W_gcn = (const float*)d_in[5];
    const float* b_gcn = (const float*)d_in[6];
    const float* aW1   = (const float*)d_in[7];
    const float* ab1   = (const float*)d_in[8];
    const float* aW2   = (const float*)d_in[9];
    const float* ab2   = (const float*)d_in[10];
    const float* vW1   = (const float*)d_in[11];
    const float* vb1   = (const float*)d_in[12];
    const float* vW2   = (const float*)d_in[13];
    const float* vb2   = (const float*)d_in[14];
    const float* mW1   = (const float*)d_in[15];
    const float* mb1   = (const float*)d_in[16];
    const float* mW2   = (const float*)d_in[17];
    const float* mb2   = (const float*)d_in[18];
    const float* ew    = (const float*)d_in[19];
    float* out = (float*)d_out;

    char* w = (char*)d_ws;
    auto alloc = [&](size_t bytes) -> void* {
        void* p = (void*)w;
        w += (bytes + 255) & ~(size_t)255;
        return p;
    };
    int*   cnt      = (int*)  alloc(TOTAL_N * 4);
    int*   rowstart = (int*)  alloc((TOTAL_N + 1) * 4);
    int*   cursor   = (int*)  alloc(TOTAL_N * 4);
    float* dinv     = (float*)alloc(TOTAL_N * 4);
    int*   csr_src  = (int*)  alloc((size_t)NE * 4);
    float* xa       = (float*)alloc((size_t)TOTAL_N * IND * 4);
    float* srow     = (float*)alloc(TOTAL_N * 4);
    u16*   g_bf     = (u16*)  alloc((size_t)TOTAL_N * Hd * 2);
    u16*   t1_bf    = (u16*)  alloc((size_t)TOTAL_N * Hd * 2);
    u16*   t_bf     = (u16*)  alloc((size_t)TOTAL_N * Hd * 2);
    float* b12      = (float*)alloc(Hd * 4);
    u16*   wt_gcn   = (u16*)  alloc((size_t)Hd * Hd * 2);
    u16*   wt_a1    = (u16*)  alloc((size_t)Hd * Hd * 2);
    u16*   wt_a2    = (u16*)  alloc((size_t)Hd * Hd * 2);
    u16*   wt_v1    = (u16*)  alloc((size_t)Hd * Hd * 2);
    u16*   wt_v2    = (u16*)  alloc((size_t)Hd * Hd * 2);
    u16*   wt_12    = (u16*)  alloc((size_t)Hd * IND * 2);

    // ---- prep: weight transposes + b12 + zero cnt ----
    WtArgs wa;
    wa.src[0] = W_gcn; wa.dst[0] = wt_gcn;
    wa.src[1] = aW1;   wa.dst[1] = wt_a1;
    wa.src[2] = aW2;   wa.dst[2] = wt_a2;
    wa.src[3] = vW1;   wa.dst[3] = wt_v1;
    wa.src[4] = vW2;   wa.dst[4] = wt_v2;
    wa.b_emb = b_emb; wa.W_gcn = W_gcn; wa.b12 = b12; wa.cnt = cnt;
    k_prep<<<209, 256, 0, stream>>>(wa);

    // ---- composite weight: wt_12 = (W_emb @ W_gcn)^T ----
    k_mfma_gemm<float, u16><<<dim3(2, 1), 256, 0, stream>>>(
        W_emb, wt_gcn, nullptr, nullptr, nullptr, wt_12, IND, Hd, 0, 1);

    // ---- CSR build ----
    k_count<<<NE / 256, 256, 0, stream>>>(edst, cnt);
    k_scan<<<1, 1024, 0, stream>>>(cnt, rowstart, cursor, dinv);
    k_scatter<<<NE / 256, 256, 0, stream>>>(esrc, edst, cursor, csr_src);

    // ---- xa = A_norm@x + x/deg ; srow ----
    k_aggx<<<TOTAL_N / 4, 256, 0, stream>>>((const float2*)x, rowstart, csr_src, dinv,
                                            (float2*)xa, srow);

    // ---- g = relu(xa@W12 + srow*b12 + b_gcn) ----
    k_mfma_gemm<float, u16><<<dim3(2, TOTAL_N / 128), 256, 0, stream>>>(
        xa, wt_12, b_gcn, srow, b12, g_bf, TOTAL_N, IND, 1, 0);

    // ---- t = relu(g@aW1+ab1)@aW2+ab2 ----
    k_mfma_gemm<u16, u16><<<dim3(2, TOTAL_N / 128), 256, 0, stream>>>(
        g_bf, wt_a1, ab1, nullptr, nullptr, t1_bf, TOTAL_N, Hd, 1, 0);
    k_mfma_gemm<u16, u16><<<dim3(2, TOTAL_N / 128), 256, 0, stream>>>(
        t1_bf, wt_a2, ab2, nullptr, nullptr, t_bf, TOTAL_N, Hd, 0, 0);

    // ---- fused per-graph tail ----
    k_graph<<<Bg, 256, 0, stream>>>(t_bf, ew, g_bf, wt_v1, vb1, wt_v2, vb2,
                                    mW1, mb1, mW2, mb2, out);
}

// Round 8
// 403.095 us; speedup vs baseline: 1.0830x; 1.0830x over previous
//
#include <hip/hip_runtime.h>
#include <hip/hip_bf16.h>

#define DEVINL __device__ __forceinline__

typedef unsigned short u16;
typedef short v8s   __attribute__((ext_vector_type(8)));
typedef float v4f   __attribute__((ext_vector_type(4)));
typedef u16   v4u16 __attribute__((ext_vector_type(4)));
typedef short v4s16 __attribute__((ext_vector_type(4)));

constexpr int Bg      = 64;
constexpr int Nn      = 512;
constexpr int Vv      = 64;
constexpr int IND     = 128;
constexpr int Hd      = 256;
constexpr int OUTD    = 10;
constexpr int TOTAL_N = Bg * Nn;    // 32768
constexpr int NE      = Bg * 16384; // 1048576

DEVINL u16 f2bf(float f) {
    unsigned u = __float_as_uint(f);
    u += 0x7FFF + ((u >> 16) & 1);   // RNE
    return (u16)(u >> 16);
}
DEVINL float bf2f(u16 s) { return __uint_as_float(((unsigned)s) << 16); }

DEVINL void ld4f(const float* p, float o[4]) {
    float4 v = *(const float4*)p;
    o[0] = v.x; o[1] = v.y; o[2] = v.z; o[3] = v.w;
}
DEVINL void ld4f(const u16* p, float o[4]) {
    v4u16 v = *(const v4u16*)p;
    o[0] = bf2f(v[0]); o[1] = bf2f(v[1]); o[2] = bf2f(v[2]); o[3] = bf2f(v[3]);
}
DEVINL void stC(float* C, size_t idx, float v) { C[idx] = v; }
DEVINL void stC(u16* C, size_t idx, float v)   { C[idx] = f2bf(v); }

// ---------------- fused prep ----------------
// blocks 0..63:    transpose-cast 4 weights [256][256] -> bf16 [n][k]
// block 64:        b12 = b_emb @ W_gcn
// blocks 65..192:  zero cnt (128 x 256 ints)
// blocks 193..224: wt_12[n][k] = sum_j W_emb[k][j]*W_gcn[j][n]  (fp32 VALU)
struct WtArgs {
    const float* src[4];
    u16* dst[4];
    const float* W_emb;
    const float* b_emb;
    const float* W_gcn;
    float* b12;
    int* cnt;
    u16* wt12;
};
__global__ __launch_bounds__(256) void k_prep(WtArgs a) {
    int bid = blockIdx.x;
    int t = threadIdx.x;
    if (bid >= 193) {
        int gtid = (bid - 193) * 256 + t;      // 0..8191
        int n = gtid >> 5;                      // 0..255
        int k4 = (gtid & 31) * 4;               // 0..124
        float a0 = 0, a1 = 0, a2 = 0, a3 = 0;
        for (int j = 0; j < Hd; j++) {
            float wg = a.W_gcn[(size_t)j * 256 + n];
            a0 += a.W_emb[(size_t)(k4 + 0) * 256 + j] * wg;
            a1 += a.W_emb[(size_t)(k4 + 1) * 256 + j] * wg;
            a2 += a.W_emb[(size_t)(k4 + 2) * 256 + j] * wg;
            a3 += a.W_emb[(size_t)(k4 + 3) * 256 + j] * wg;
        }
        v4u16 o;
        o[0] = f2bf(a0); o[1] = f2bf(a1); o[2] = f2bf(a2); o[3] = f2bf(a3);
        *(v4u16*)&a.wt12[(size_t)n * IND + k4] = o;
        return;
    }
    if (bid >= 65) {
        a.cnt[(bid - 65) * 256 + t] = 0;
        return;
    }
    if (bid == 64) {
        float acc = 0.f;
        for (int k = 0; k < IND; k++) acc += a.b_emb[k] * a.W_gcn[(size_t)k * 256 + t];
        a.b12[t] = acc;
        return;
    }
    int mi = bid / 16, tile = bid % 16;
    int k0 = (tile & 3) * 64, n0 = (tile >> 2) * 64;
    const float* src = a.src[mi];
    u16* dst = a.dst[mi];
    __shared__ float T[64][65];
#pragma unroll
    for (int j = 0; j < 16; j++) {
        int idx = t + 256 * j;
        int r = idx >> 6, c = idx & 63;
        T[c][r] = src[(size_t)(k0 + r) * 256 + n0 + c];
    }
    __syncthreads();
#pragma unroll
    for (int j = 0; j < 16; j++) {
        int idx = t + 256 * j;
        int nr = idx >> 6, kc = idx & 63;
        dst[(size_t)(n0 + nr) * 256 + k0 + kc] = f2bf(T[nr][kc]);
    }
}

// ---------------- edge count ----------------
__global__ void k_count(const int* __restrict__ edst, int* __restrict__ cnt) {
    int e = blockIdx.x * blockDim.x + threadIdx.x;
    if (e < NE) atomicAdd(&cnt[edst[e]], 1);
}

// ---------------- exclusive scan over 32768 counts ----------------
__global__ __launch_bounds__(1024) void k_scan(const int* __restrict__ cnt,
                                               int* __restrict__ rowstart,
                                               int* __restrict__ cursor,
                                               float* __restrict__ dinv) {
    __shared__ int part[1024];
    int t = threadIdx.x;
    int base = t * 32;
    int local[32];
    int s = 0;
#pragma unroll
    for (int i = 0; i < 32; i++) { local[i] = cnt[base + i]; s += local[i]; }
    part[t] = s;
    __syncthreads();
    for (int off = 1; off < 1024; off <<= 1) {
        int v = (t >= off) ? part[t - off] : 0;
        __syncthreads();
        part[t] += v;
        __syncthreads();
    }
    int run = part[t] - s;
#pragma unroll
    for (int i = 0; i < 32; i++) {
        int idx = base + i;
        rowstart[idx] = run;
        cursor[idx]   = run;
        dinv[idx] = rsqrtf((float)(local[i] + 1));
        run += local[i];
    }
    if (t == 0) rowstart[TOTAL_N] = NE;
}

// ---------------- scatter edges into CSR (src + coef) ----------------
__global__ void k_scatter(const int* __restrict__ esrc, const int* __restrict__ edst,
                          int* __restrict__ cursor, const float* __restrict__ dinv,
                          int* __restrict__ csr_src, float* __restrict__ csr_coef) {
    int e = blockIdx.x * blockDim.x + threadIdx.x;
    if (e >= NE) return;
    int s = esrc[e], d = edst[e];
    int pos = atomicAdd(&cursor[d], 1);
    csr_src[pos]  = s;
    csr_coef[pos] = dinv[s] * dinv[d];
}

// ---------------- aggregate x: xa = A_norm@x + x/deg ; srow ----------------
// one node per block, 128 threads (one channel each), 4-way batched gathers.
__global__ __launch_bounds__(128) void k_aggx(const float* __restrict__ x,
                                              const int* __restrict__ rowstart,
                                              const int* __restrict__ csr_src,
                                              const float* __restrict__ csr_coef,
                                              const float* __restrict__ dinv,
                                              float* __restrict__ xa,
                                              float* __restrict__ srow) {
    __shared__ int   lsrc[128];
    __shared__ float lcoef[128];
    // XCD swizzle: 32768 blocks; b>>3 in [0,4096)=2^12 -> XCD id bits [12:14]
    int node = ((blockIdx.x & 7) << 12) | (blockIdx.x >> 3);
    int ch = threadIdx.x;
    float di = dinv[node];
    float invdeg = di * di;
    float acc = x[(size_t)node * IND + ch] * invdeg;
    float csum = 0.f;
    int rs0 = rowstart[node], rs1 = rowstart[node + 1];
    for (int base = rs0; base < rs1; base += 128) {
        int e = base + ch;
        if (e < rs1) { lsrc[ch] = csr_src[e]; lcoef[ch] = csr_coef[e]; }
        __syncthreads();
        int m = min(128, rs1 - base);
        int i = 0;
        for (; i + 4 <= m; i += 4) {
            int   s0 = lsrc[i],  s1 = lsrc[i + 1],  s2 = lsrc[i + 2],  s3 = lsrc[i + 3];
            float c0 = lcoef[i], c1 = lcoef[i + 1], c2 = lcoef[i + 2], c3 = lcoef[i + 3];
            float v0 = x[(size_t)s0 * IND + ch];
            float v1 = x[(size_t)s1 * IND + ch];
            float v2 = x[(size_t)s2 * IND + ch];
            float v3 = x[(size_t)s3 * IND + ch];
            acc += v0 * c0; acc += v1 * c1; acc += v2 * c2; acc += v3 * c3;
            csum += c0 + c1 + c2 + c3;
        }
        for (; i < m; i++) {
            float c = lcoef[i];
            acc += x[(size_t)lsrc[i] * IND + ch] * c;
            csum += c;
        }
        __syncthreads();
    }
    xa[(size_t)node * IND + ch] = acc;
    if (ch == 0) srow[node] = invdeg + csum;
}

// ---------------- MFMA GEMM: C[M,256] = A[M,K] @ W[K,256] epilogues ------------
template <typename TA, typename TC>
__global__ __launch_bounds__(256) void k_mfma_gemm(const TA* __restrict__ A,
                                                   const u16* __restrict__ Wt,
                                                   const float* __restrict__ bias,
                                                   const float* __restrict__ srow,
                                                   const float* __restrict__ b12v,
                                                   TC* __restrict__ C,
                                                   int M, int K, int relu) {
    constexpr int LDK = 88;
    __shared__ short As[128 * LDK];
    __shared__ short Bs[128 * LDK];
    int tid  = threadIdx.x;
    int row0 = blockIdx.y * 128, col0 = blockIdx.x * 128;
    int lane = tid & 63, wid = tid >> 6;
    int wm = (wid >> 1) * 64, wn = (wid & 1) * 64;
    int q = lane >> 4, r = lane & 15;
    v4f acc[4][4];
#pragma unroll
    for (int i = 0; i < 4; i++)
#pragma unroll
        for (int j = 0; j < 4; j++) acc[i][j] = (v4f){0.f, 0.f, 0.f, 0.f};
    int sm = tid >> 1, sk = (tid & 1) * 32;
    for (int k0 = 0; k0 < K; k0 += 64) {
        const TA* ap  = A  + (size_t)(row0 + sm) * K + k0 + sk;
        const u16* bp = Wt + (size_t)(col0 + sm) * K + k0 + sk;
        short* adst = &As[sm * LDK + sk];
        short* bdst = &Bs[sm * LDK + sk];
#pragma unroll
        for (int i = 0; i < 8; i++) {
            float o[4];
            ld4f(ap + 4 * i, o);
            v4s16 pa;
            pa[0] = (short)f2bf(o[0]); pa[1] = (short)f2bf(o[1]);
            pa[2] = (short)f2bf(o[2]); pa[3] = (short)f2bf(o[3]);
            *(v4s16*)(adst + 4 * i) = pa;
            *(v4u16*)(bdst + 4 * i) = *(const v4u16*)(bp + 4 * i);
        }
        __syncthreads();
#pragma unroll
        for (int ks = 0; ks < 64; ks += 32) {
            v8s af[4], bfr[4];
#pragma unroll
            for (int i = 0; i < 4; i++)
                af[i] = *(const v8s*)&As[(wm + i * 16 + r) * LDK + ks + q * 8];
#pragma unroll
            for (int j = 0; j < 4; j++)
                bfr[j] = *(const v8s*)&Bs[(wn + j * 16 + r) * LDK + ks + q * 8];
#pragma unroll
            for (int i = 0; i < 4; i++)
#pragma unroll
                for (int j = 0; j < 4; j++)
                    acc[i][j] = __builtin_amdgcn_mfma_f32_16x16x32_bf16(af[i], bfr[j], acc[i][j], 0, 0, 0);
        }
        __syncthreads();
    }
#pragma unroll
    for (int i = 0; i < 4; i++) {
#pragma unroll
        for (int j = 0; j < 4; j++) {
            int col = col0 + wn + j * 16 + r;
            float bcol = bias ? bias[col] : 0.f;
            float b12c = b12v ? b12v[col] : 0.f;
#pragma unroll
            for (int rg = 0; rg < 4; rg++) {
                int row = row0 + wm + i * 16 + q * 4 + rg;
                float v = acc[i][j][rg] + bcol;
                if (srow) v += srow[row] * b12c;
                if (relu) v = fmaxf(v, 0.f);
                stC(C, (size_t)row * 256 + col, v);
            }
        }
    }
}

// ---------------- fused proto + att (one block per graph, 1024 thr) ----------------
__global__ __launch_bounds__(1024) void k_proto_att(const u16* __restrict__ t,
                                                    const float* __restrict__ ew,
                                                    float* __restrict__ scale) {
    __shared__ float part[4][256];
    __shared__ float protos[256];
    __shared__ float red[256];
    __shared__ float pns;
    int b = blockIdx.x, tid = threadIdx.x;
    int st = tid >> 8, ch = tid & 255;
    float sm = 0.f;
    int n0 = st * 128;
    for (int n = n0; n < n0 + 128; n++)
        sm += bf2f(t[(size_t)(b * Nn + n) * Hd + ch]);
    part[st][ch] = sm;
    __syncthreads();
    if (tid < 256) {
        float p = (part[0][ch] + part[1][ch] + part[2][ch] + part[3][ch]) * (1.f / (float)Nn);
        protos[ch] = p;
        red[ch] = p * p;
    }
    __syncthreads();
    for (int off = 128; off > 0; off >>= 1) {
        if (tid < off) red[tid] += red[tid + off];
        __syncthreads();
    }
    if (tid == 0) pns = fmaxf(sqrtf(red[0]), 1e-8f);
    __syncthreads();
    float pnb = pns;
    int lane = tid & 63, wv = tid >> 6;   // 16 waves
    float4 pv4 = *(const float4*)&protos[lane * 4];
    for (int n = wv; n < Nn; n += 16) {
        int node = b * Nn + n;
        v4u16 tv4 = *(const v4u16*)&t[(size_t)node * Hd + lane * 4];
        float t0 = bf2f(tv4[0]), t1 = bf2f(tv4[1]), t2 = bf2f(tv4[2]), t3 = bf2f(tv4[3]);
        float dot = t0 * pv4.x + t1 * pv4.y + t2 * pv4.z + t3 * pv4.w;
        float sq  = t0 * t0 + t1 * t1 + t2 * t2 + t3 * t3;
        float wvv = ew[(size_t)node * Vv + lane];
#pragma unroll
        for (int off = 32; off > 0; off >>= 1) {
            dot += __shfl_xor(dot, off);
            sq  += __shfl_xor(sq, off);
            wvv += __shfl_xor(wvv, off);
        }
        if (lane == 0) {
            float tn  = fmaxf(sqrtf(sq), 1e-8f);
            float sim = dot / (tn * pnb);
            float att = 0.5f * (1.f + sim);
            float rs  = att * wvv;
            float den = (rs == 0.f) ? 1.f : rs;
            scale[node] = att / den;
        }
    }
}

// ---------------- vn[b] = (ew*scale)^T @ g[b] : per-graph MFMA GEMM ----------
constexpr int LDV = 36;
DEVINL v8s ld_frag36(const short* p) {
    v4s16 lo = *(const v4s16*)p;
    v4s16 hi = *(const v4s16*)(p + 4);
    v8s f;
    f[0] = lo[0]; f[1] = lo[1]; f[2] = lo[2]; f[3] = lo[3];
    f[4] = hi[0]; f[5] = hi[1]; f[6] = hi[2]; f[7] = hi[3];
    return f;
}
__global__ __launch_bounds__(256) void k_vn_mfma(const float* __restrict__ ew,
                                                 const float* __restrict__ scale,
                                                 const u16* __restrict__ g,
                                                 u16* __restrict__ vn) {
    __shared__ short As[64 * LDV];
    __shared__ short Bs[256 * LDV];
    int b = blockIdx.x;
    int tid = threadIdx.x;
    int lane = tid & 63, wid = tid >> 6;
    int h0 = wid * 64;
    int q = lane >> 4, r = lane & 15;
    v4f acc[4][4];
#pragma unroll
    for (int i = 0; i < 4; i++)
#pragma unroll
        for (int j = 0; j < 4; j++) acc[i][j] = (v4f){0.f, 0.f, 0.f, 0.f};
    for (int k0 = 0; k0 < Nn; k0 += 32) {
#pragma unroll
        for (int p = 0; p < 8; p++) {
            int e = tid + 256 * p;
            int nl = e >> 6, v = e & 63;
            int n = b * Nn + k0 + nl;
            As[v * LDV + nl] = (short)f2bf(ew[(size_t)n * Vv + v] * scale[n]);
        }
#pragma unroll
        for (int p = 0; p < 8; p++) {
            int e = tid + 256 * p;
            int h = e & 255, kgrp = e >> 8;
            int kl = kgrp * 4;
            v4s16 tmp;
#pragma unroll
            for (int c = 0; c < 4; c++)
                tmp[c] = (short)g[(size_t)(b * Nn + k0 + kl + c) * Hd + h];
            *(v4s16*)&Bs[h * LDV + kl] = tmp;
        }
        __syncthreads();
        v8s af[4], bfr[4];
#pragma unroll
        for (int i = 0; i < 4; i++)
            af[i] = ld_frag36(&As[(i * 16 + r) * LDV + q * 8]);
#pragma unroll
        for (int j = 0; j < 4; j++)
            bfr[j] = ld_frag36(&Bs[(h0 + j * 16 + r) * LDV + q * 8]);
#pragma unroll
        for (int i = 0; i < 4; i++)
#pragma unroll
            for (int j = 0; j < 4; j++)
                acc[i][j] = __builtin_amdgcn_mfma_f32_16x16x32_bf16(af[i], bfr[j], acc[i][j], 0, 0, 0);
        __syncthreads();
    }
#pragma unroll
    for (int i = 0; i < 4; i++)
#pragma unroll
        for (int j = 0; j < 4; j++) {
            int col = h0 + j * 16 + r;
#pragma unroll
            for (int rg = 0; rg < 4; rg++) {
                int v = i * 16 + q * 4 + rg;
                vn[(size_t)(b * Vv + v) * Hd + col] = f2bf(acc[i][j][rg]);
            }
        }
}

// ---------------- head: gf = mean_v vn2 ; out = relu(gf@mW1+mb1)@mW2+mb2 ------
__global__ __launch_bounds__(256) void k_head(const float* __restrict__ vn2,
                                              const float* __restrict__ mW1,
                                              const float* __restrict__ mb1,
                                              const float* __restrict__ mW2,
                                              const float* __restrict__ mb2,
                                              float* __restrict__ out) {
    __shared__ float gfs[256];
    __shared__ float zs[256];
    int b = blockIdx.x, t = threadIdx.x;
    float s = 0.f;
    for (int v = 0; v < Vv; v++) s += vn2[(size_t)(b * Vv + v) * Hd + t];
    gfs[t] = s * (1.f / (float)Vv);
    __syncthreads();
    float z = mb1[t];
    for (int k = 0; k < Hd; k++) z += gfs[k] * mW1[k * Hd + t];
    zs[t] = fmaxf(z, 0.f);
    __syncthreads();
    if (t < OUTD) {
        float o = mb2[t];
        for (int ch = 0; ch < Hd; ch++) o += zs[ch] * mW2[ch * OUTD + t];
        out[b * OUTD + t] = o;
    }
}

// =======================================================================
extern "C" void kernel_launch(void* const* d_in, const int* in_sizes, int n_in,
                              void* d_out, int out_size, void* d_ws, size_t ws_size,
                              hipStream_t stream) {
    const float* x     = (const float*)d_in[0];
    const int*   esrc  = (const int*)d_in[1];
    const int*   edst  = (const int*)d_in[2];
    const float* W_emb = (const float*)d_in[3];
    const float* b_emb = (const float*)d_in[4];
    const float* W_gcn = (const float*)d_in[5];
    const float* b_gcn = (const float*)d_in[6];
    const float* aW1   = (const float*)d_in[7];
    const float* ab1   = (const float*)d_in[8];
    const float* aW2   = (const float*)d_in[9];
    const float* ab2   = (const float*)d_in[10];
    const float* vW1   = (const float*)d_in[11];
    const float* vb1   = (const float*)d_in[12];
    const float* vW2   = (const float*)d_in[13];
    const float* vb2   = (const float*)d_in[14];
    const float* mW1   = (const float*)d_in[15];
    const float* mb1   = (const float*)d_in[16];
    const float* mW2   = (const float*)d_in[17];
    const float* mb2   = (const float*)d_in[18];
    const float* ew    = (const float*)d_in[19];
    float* out = (float*)d_out;

    char* w = (char*)d_ws;
    auto alloc = [&](size_t bytes) -> void* {
        void* p = (void*)w;
        w += (bytes + 255) & ~(size_t)255;
        return p;
    };
    int*   cnt      = (int*)  alloc(TOTAL_N * 4);
    int*   rowstart = (int*)  alloc((TOTAL_N + 1) * 4);
    int*   cursor   = (int*)  alloc(TOTAL_N * 4);
    float* dinv     = (float*)alloc(TOTAL_N * 4);
    int*   csr_src  = (int*)  alloc((size_t)NE * 4);
    float* csr_coef = (float*)alloc((size_t)NE * 4);
    float* xa       = (float*)alloc((size_t)TOTAL_N * IND * 4);
    float* srow     = (float*)alloc(TOTAL_N * 4);
    u16*   g_bf     = (u16*)  alloc((size_t)TOTAL_N * Hd * 2);
    u16*   t1_bf    = (u16*)  alloc((size_t)TOTAL_N * Hd * 2);
    u16*   t_bf     = (u16*)  alloc((size_t)TOTAL_N * Hd * 2);
    u16*   vn_bf    = (u16*)  alloc((size_t)Bg * Vv * Hd * 2);
    u16*   vtmp_bf  = (u16*)  alloc((size_t)Bg * Vv * Hd * 2);
    float* vn2      = (float*)alloc((size_t)Bg * Vv * Hd * 4);
    float* scale    = (float*)alloc(TOTAL_N * 4);
    float* b12      = (float*)alloc(Hd * 4);
    u16*   wt_a1    = (u16*)  alloc((size_t)Hd * Hd * 2);
    u16*   wt_a2    = (u16*)  alloc((size_t)Hd * Hd * 2);
    u16*   wt_v1    = (u16*)  alloc((size_t)Hd * Hd * 2);
    u16*   wt_v2    = (u16*)  alloc((size_t)Hd * Hd * 2);
    u16*   wt_12    = (u16*)  alloc((size_t)Hd * IND * 2);

    // ---- prep: weight transposes + b12 + zero cnt + wt12 ----
    WtArgs wa;
    wa.src[0] = aW1; wa.dst[0] = wt_a1;
    wa.src[1] = aW2; wa.dst[1] = wt_a2;
    wa.src[2] = vW1; wa.dst[2] = wt_v1;
    wa.src[3] = vW2; wa.dst[3] = wt_v2;
    wa.W_emb = W_emb; wa.b_emb = b_emb; wa.W_gcn = W_gcn;
    wa.b12 = b12; wa.cnt = cnt; wa.wt12 = wt_12;
    k_prep<<<225, 256, 0, stream>>>(wa);

    // ---- CSR build ----
    k_count<<<NE / 256, 256, 0, stream>>>(edst, cnt);
    k_scan<<<1, 1024, 0, stream>>>(cnt, rowstart, cursor, dinv);
    k_scatter<<<NE / 256, 256, 0, stream>>>(esrc, edst, cursor, dinv, csr_src, csr_coef);

    // ---- xa = A_norm@x + x/deg ; srow ----
    k_aggx<<<TOTAL_N, 128, 0, stream>>>(x, rowstart, csr_src, csr_coef, dinv, xa, srow);

    // ---- g = relu(xa@W12 + srow*b12 + b_gcn) ----
    k_mfma_gemm<float, u16><<<dim3(2, TOTAL_N / 128), 256, 0, stream>>>(
        xa, wt_12, b_gcn, srow, b12, g_bf, TOTAL_N, IND, 1);

    // ---- t = relu(g@aW1+ab1)@aW2+ab2 ----
    k_mfma_gemm<u16, u16><<<dim3(2, TOTAL_N / 128), 256, 0, stream>>>(
        g_bf, wt_a1, ab1, nullptr, nullptr, t1_bf, TOTAL_N, Hd, 1);
    k_mfma_gemm<u16, u16><<<dim3(2, TOTAL_N / 128), 256, 0, stream>>>(
        t1_bf, wt_a2, ab2, nullptr, nullptr, t_bf, TOTAL_N, Hd, 0);

    // ---- fused proto + att scale ----
    k_proto_att<<<Bg, 1024, 0, stream>>>(t_bf, ew, scale);

    // ---- vn = (ew*scale)^T @ g per graph (MFMA) ----
    k_vn_mfma<<<Bg, 256, 0, stream>>>(ew, scale, g_bf, vn_bf);

    // ---- vn MLP ----
    k_mfma_gemm<u16, u16><<<dim3(2, (Bg * Vv) / 128), 256, 0, stream>>>(
        vn_bf, wt_v1, vb1, nullptr, nullptr, vtmp_bf, Bg * Vv, Hd, 1);
    k_mfma_gemm<u16, float><<<dim3(2, (Bg * Vv) / 128), 256, 0, stream>>>(
        vtmp_bf, wt_v2, vb2, nullptr, nullptr, vn2, Bg * Vv, Hd, 0);

    // ---- head ----
    k_head<<<Bg, 256, 0, stream>>>(vn2, mW1, mb1, mW2, mb2, out);
}

// Round 9
// 399.174 us; speedup vs baseline: 1.0937x; 1.0098x over previous
//
#include <hip/hip_runtime.h>
#include <hip/hip_bf16.h>

#define DEVINL __device__ __forceinline__

typedef unsigned short u16;
typedef short v8s   __attribute__((ext_vector_type(8)));
typedef float v4f   __attribute__((ext_vector_type(4)));
typedef u16   v4u16 __attribute__((ext_vector_type(4)));
typedef short v4s16 __attribute__((ext_vector_type(4)));

constexpr int Bg      = 64;
constexpr int Nn      = 512;
constexpr int Vv      = 64;
constexpr int IND     = 128;
constexpr int Hd      = 256;
constexpr int OUTD    = 10;
constexpr int TOTAL_N = Bg * Nn;    // 32768
constexpr int NE      = Bg * 16384; // 1048576

DEVINL u16 f2bf(float f) {
    unsigned u = __float_as_uint(f);
    u += 0x7FFF + ((u >> 16) & 1);   // RNE
    return (u16)(u >> 16);
}
DEVINL float bf2f(u16 s) { return __uint_as_float(((unsigned)s) << 16); }

DEVINL void stC(float* C, size_t idx, float v) { C[idx] = v; }
DEVINL void stC(u16* C, size_t idx, float v)   { C[idx] = f2bf(v); }

// staging helpers: fp32 converts, bf16 copies straight through
DEVINL void stage4(const float* p, short* d) {
    float4 v = *(const float4*)p;
    v4s16 pa;
    pa[0] = (short)f2bf(v.x); pa[1] = (short)f2bf(v.y);
    pa[2] = (short)f2bf(v.z); pa[3] = (short)f2bf(v.w);
    *(v4s16*)d = pa;
}
DEVINL void stage4(const u16* p, short* d) { *(v4u16*)d = *(const v4u16*)p; }

// ---------------- fused prep ----------------
// blocks 0..63:    transpose-cast 4 weights [256][256] -> bf16 [n][k]
// block 64:        b12 = b_emb @ W_gcn
// blocks 65..192:  zero cnt (128 x 256 ints)
// blocks 193..224: wt_12[n][k] = sum_j W_emb[k][j]*W_gcn[j][n]  (fp32 VALU)
struct WtArgs {
    const float* src[4];
    u16* dst[4];
    const float* W_emb;
    const float* b_emb;
    const float* W_gcn;
    float* b12;
    int* cnt;
    u16* wt12;
};
__global__ __launch_bounds__(256) void k_prep(WtArgs a) {
    int bid = blockIdx.x;
    int t = threadIdx.x;
    if (bid >= 193) {
        int gtid = (bid - 193) * 256 + t;      // 0..8191
        int n = gtid >> 5;                      // 0..255
        int k4 = (gtid & 31) * 4;               // 0..124
        float a0 = 0, a1 = 0, a2 = 0, a3 = 0;
        for (int j = 0; j < Hd; j++) {
            float wg = a.W_gcn[(size_t)j * 256 + n];
            a0 += a.W_emb[(size_t)(k4 + 0) * 256 + j] * wg;
            a1 += a.W_emb[(size_t)(k4 + 1) * 256 + j] * wg;
            a2 += a.W_emb[(size_t)(k4 + 2) * 256 + j] * wg;
            a3 += a.W_emb[(size_t)(k4 + 3) * 256 + j] * wg;
        }
        v4u16 o;
        o[0] = f2bf(a0); o[1] = f2bf(a1); o[2] = f2bf(a2); o[3] = f2bf(a3);
        *(v4u16*)&a.wt12[(size_t)n * IND + k4] = o;
        return;
    }
    if (bid >= 65) {
        a.cnt[(bid - 65) * 256 + t] = 0;
        return;
    }
    if (bid == 64) {
        float acc = 0.f;
        for (int k = 0; k < IND; k++) acc += a.b_emb[k] * a.W_gcn[(size_t)k * 256 + t];
        a.b12[t] = acc;
        return;
    }
    int mi = bid / 16, tile = bid % 16;
    int k0 = (tile & 3) * 64, n0 = (tile >> 2) * 64;
    const float* src = a.src[mi];
    u16* dst = a.dst[mi];
    __shared__ float T[64][65];
#pragma unroll
    for (int j = 0; j < 16; j++) {
        int idx = t + 256 * j;
        int r = idx >> 6, c = idx & 63;
        T[c][r] = src[(size_t)(k0 + r) * 256 + n0 + c];
    }
    __syncthreads();
#pragma unroll
    for (int j = 0; j < 16; j++) {
        int idx = t + 256 * j;
        int nr = idx >> 6, kc = idx & 63;
        dst[(size_t)(n0 + nr) * 256 + k0 + kc] = f2bf(T[nr][kc]);
    }
}

// ---------------- edge count ----------------
__global__ void k_count(const int* __restrict__ edst, int* __restrict__ cnt) {
    int e = blockIdx.x * blockDim.x + threadIdx.x;
    if (e < NE) atomicAdd(&cnt[edst[e]], 1);
}

// ---------------- exclusive scan over 32768 counts ----------------
__global__ __launch_bounds__(1024) void k_scan(const int* __restrict__ cnt,
                                               int* __restrict__ rowstart,
                                               int* __restrict__ cursor,
                                               float* __restrict__ dinv) {
    __shared__ int part[1024];
    int t = threadIdx.x;
    int base = t * 32;
    int local[32];
    int s = 0;
#pragma unroll
    for (int i = 0; i < 32; i++) { local[i] = cnt[base + i]; s += local[i]; }
    part[t] = s;
    __syncthreads();
    for (int off = 1; off < 1024; off <<= 1) {
        int v = (t >= off) ? part[t - off] : 0;
        __syncthreads();
        part[t] += v;
        __syncthreads();
    }
    int run = part[t] - s;
#pragma unroll
    for (int i = 0; i < 32; i++) {
        int idx = base + i;
        rowstart[idx] = run;
        cursor[idx]   = run;
        dinv[idx] = rsqrtf((float)(local[i] + 1));
        run += local[i];
    }
    if (t == 0) rowstart[TOTAL_N] = NE;
}

// ---------------- scatter edges into CSR (packed src+coef, one 8B store) ------
__global__ void k_scatter(const int* __restrict__ esrc, const int* __restrict__ edst,
                          int* __restrict__ cursor, const float* __restrict__ dinv,
                          int2* __restrict__ csr) {
    int e = blockIdx.x * blockDim.x + threadIdx.x;
    if (e >= NE) return;
    int s = esrc[e], d = edst[e];
    int pos = atomicAdd(&cursor[d], 1);
    int2 sc;
    sc.x = s;
    sc.y = __float_as_int(dinv[s] * dinv[d]);
    csr[pos] = sc;
}

// ---------------- aggregate x: xa = A_norm@x + x/deg ; srow (bf16 out) --------
// one wave per node (4 nodes/block), float2 per lane, readlane-scalarized
// broadcast: coef/src become SGPRs -> scalar addr math + 1-SGPR-operand FMAs.
__global__ __launch_bounds__(256) void k_aggx(const float2* __restrict__ x2,
                                              const int* __restrict__ rowstart,
                                              const int2* __restrict__ csr,
                                              const float* __restrict__ dinv,
                                              u16* __restrict__ xa_bf,
                                              float* __restrict__ srow) {
    int tid = threadIdx.x;
    int lane = tid & 63, w = tid >> 6;
    // XCD swizzle: 8192 blocks; b>>3 in [0,1024)=2^10 -> XCD id bits [10:12]
    int swb = ((blockIdx.x & 7) << 10) | (blockIdx.x >> 3);
    int node = swb * 4 + w;
    float di = dinv[node];
    float invdeg = di * di;
    float2 xv0 = x2[(size_t)node * 64 + lane];
    float ax = xv0.x * invdeg, ay = xv0.y * invdeg;
    float csum = 0.f;
    int rs0 = rowstart[node], rs1 = rowstart[node + 1];
    for (int base = rs0; base < rs1; base += 64) {
        int e = base + lane;
        int s = 0; float c = 0.f;
        if (e < rs1) {
            int2 sc = csr[e];
            s = sc.x;
            c = __int_as_float(sc.y);
            csum += c;
        }
        int m = rs1 - base; if (m > 64) m = 64;
        for (int i = 0; i < m; i += 8) {   // lanes beyond m have c=0 (harmless)
            int   ss[8]; float cc[8]; float2 vv[8];
#pragma unroll
            for (int u = 0; u < 8; u++) {
                ss[u] = __builtin_amdgcn_readlane(s, i + u);
                cc[u] = __int_as_float(__builtin_amdgcn_readlane(__float_as_int(c), i + u));
            }
#pragma unroll
            for (int u = 0; u < 8; u++) vv[u] = x2[(size_t)ss[u] * 64 + lane];
#pragma unroll
            for (int u = 0; u < 8; u++) { ax += vv[u].x * cc[u]; ay += vv[u].y * cc[u]; }
        }
    }
    unsigned packed = (unsigned)f2bf(ax) | ((unsigned)f2bf(ay) << 16);
    *(unsigned*)&xa_bf[(size_t)node * IND + lane * 2] = packed;
#pragma unroll
    for (int off = 32; off > 0; off >>= 1) csum += __shfl_xor(csum, off);
    if (lane == 0) srow[node] = invdeg + csum;
}

// ---------------- MFMA GEMM: C[M,256] = A[M,K] @ W[K,256] epilogues ------------
template <typename TA, typename TC>
__global__ __launch_bounds__(256) void k_mfma_gemm(const TA* __restrict__ A,
                                                   const u16* __restrict__ Wt,
                                                   const float* __restrict__ bias,
                                                   const float* __restrict__ srow,
                                                   const float* __restrict__ b12v,
                                                   TC* __restrict__ C,
                                                   int M, int K, int relu) {
    constexpr int LDK = 88;
    __shared__ short As[128 * LDK];
    __shared__ short Bs[128 * LDK];
    int tid  = threadIdx.x;
    int row0 = blockIdx.y * 128, col0 = blockIdx.x * 128;
    int lane = tid & 63, wid = tid >> 6;
    int wm = (wid >> 1) * 64, wn = (wid & 1) * 64;
    int q = lane >> 4, r = lane & 15;
    v4f acc[4][4];
#pragma unroll
    for (int i = 0; i < 4; i++)
#pragma unroll
        for (int j = 0; j < 4; j++) acc[i][j] = (v4f){0.f, 0.f, 0.f, 0.f};
    int sm = tid >> 1, sk = (tid & 1) * 32;
    for (int k0 = 0; k0 < K; k0 += 64) {
        const TA* ap  = A  + (size_t)(row0 + sm) * K + k0 + sk;
        const u16* bp = Wt + (size_t)(col0 + sm) * K + k0 + sk;
        short* adst = &As[sm * LDK + sk];
        short* bdst = &Bs[sm * LDK + sk];
#pragma unroll
        for (int i = 0; i < 8; i++) {
            stage4(ap + 4 * i, adst + 4 * i);
            *(v4u16*)(bdst + 4 * i) = *(const v4u16*)(bp + 4 * i);
        }
        __syncthreads();
#pragma unroll
        for (int ks = 0; ks < 64; ks += 32) {
            v8s af[4], bfr[4];
#pragma unroll
            for (int i = 0; i < 4; i++)
                af[i] = *(const v8s*)&As[(wm + i * 16 + r) * LDK + ks + q * 8];
#pragma unroll
            for (int j = 0; j < 4; j++)
                bfr[j] = *(const v8s*)&Bs[(wn + j * 16 + r) * LDK + ks + q * 8];
#pragma unroll
            for (int i = 0; i < 4; i++)
#pragma unroll
                for (int j = 0; j < 4; j++)
                    acc[i][j] = __builtin_amdgcn_mfma_f32_16x16x32_bf16(af[i], bfr[j], acc[i][j], 0, 0, 0);
        }
        __syncthreads();
    }
#pragma unroll
    for (int i = 0; i < 4; i++) {
#pragma unroll
        for (int j = 0; j < 4; j++) {
            int col = col0 + wn + j * 16 + r;
            float bcol = bias ? bias[col] : 0.f;
            float b12c = b12v ? b12v[col] : 0.f;
#pragma unroll
            for (int rg = 0; rg < 4; rg++) {
                int row = row0 + wm + i * 16 + q * 4 + rg;
                float v = acc[i][j][rg] + bcol;
                if (srow) v += srow[row] * b12c;
                if (relu) v = fmaxf(v, 0.f);
                stC(C, (size_t)row * 256 + col, v);
            }
        }
    }
}

// ---------------- fused proto + att (one block per graph, 1024 thr) ----------------
__global__ __launch_bounds__(1024) void k_proto_att(const u16* __restrict__ t,
                                                    const float* __restrict__ ew,
                                                    float* __restrict__ scale) {
    __shared__ float part[4][256];
    __shared__ float protos[256];
    __shared__ float red[256];
    __shared__ float pns;
    int b = blockIdx.x, tid = threadIdx.x;
    int st = tid >> 8, ch = tid & 255;
    float sm = 0.f;
    int n0 = st * 128;
    for (int n = n0; n < n0 + 128; n++)
        sm += bf2f(t[(size_t)(b * Nn + n) * Hd + ch]);
    part[st][ch] = sm;
    __syncthreads();
    if (tid < 256) {
        float p = (part[0][ch] + part[1][ch] + part[2][ch] + part[3][ch]) * (1.f / (float)Nn);
        protos[ch] = p;
        red[ch] = p * p;
    }
    __syncthreads();
    for (int off = 128; off > 0; off >>= 1) {
        if (tid < off) red[tid] += red[tid + off];
        __syncthreads();
    }
    if (tid == 0) pns = fmaxf(sqrtf(red[0]), 1e-8f);
    __syncthreads();
    float pnb = pns;
    int lane = tid & 63, wv = tid >> 6;   // 16 waves
    float4 pv4 = *(const float4*)&protos[lane * 4];
    for (int n = wv; n < Nn; n += 16) {
        int node = b * Nn + n;
        v4u16 tv4 = *(const v4u16*)&t[(size_t)node * Hd + lane * 4];
        float t0 = bf2f(tv4[0]), t1 = bf2f(tv4[1]), t2 = bf2f(tv4[2]), t3 = bf2f(tv4[3]);
        float dot = t0 * pv4.x + t1 * pv4.y + t2 * pv4.z + t3 * pv4.w;
        float sq  = t0 * t0 + t1 * t1 + t2 * t2 + t3 * t3;
        float wvv = ew[(size_t)node * Vv + lane];
#pragma unroll
        for (int off = 32; off > 0; off >>= 1) {
            dot += __shfl_xor(dot, off);
            sq  += __shfl_xor(sq, off);
            wvv += __shfl_xor(wvv, off);
        }
        if (lane == 0) {
            float tn  = fmaxf(sqrtf(sq), 1e-8f);
            float sim = dot / (tn * pnb);
            float att = 0.5f * (1.f + sim);
            float rs  = att * wvv;
            float den = (rs == 0.f) ? 1.f : rs;
            scale[node] = att / den;
        }
    }
}

// ---------------- vn[b] = (ew*scale)^T @ g[b] : per-graph MFMA GEMM ----------
constexpr int LDV = 36;
DEVINL v8s ld_frag36(const short* p) {
    v4s16 lo = *(const v4s16*)p;
    v4s16 hi = *(const v4s16*)(p + 4);
    v8s f;
    f[0] = lo[0]; f[1] = lo[1]; f[2] = lo[2]; f[3] = lo[3];
    f[4] = hi[0]; f[5] = hi[1]; f[6] = hi[2]; f[7] = hi[3];
    return f;
}
__global__ __launch_bounds__(256) void k_vn_mfma(const float* __restrict__ ew,
                                                 const float* __restrict__ scale,
                                                 const u16* __restrict__ g,
                                                 u16* __restrict__ vn) {
    __shared__ short As[64 * LDV];
    __shared__ short Bs[256 * LDV];
    int b = blockIdx.x;
    int tid = threadIdx.x;
    int lane = tid & 63, wid = tid >> 6;
    int h0 = wid * 64;
    int q = lane >> 4, r = lane & 15;
    v4f acc[4][4];
#pragma unroll
    for (int i = 0; i < 4; i++)
#pragma unroll
        for (int j = 0; j < 4; j++) acc[i][j] = (v4f){0.f, 0.f, 0.f, 0.f};
    for (int k0 = 0; k0 < Nn; k0 += 32) {
#pragma unroll
        for (int p = 0; p < 8; p++) {
            int e = tid + 256 * p;
            int nl = e >> 6, v = e & 63;
            int n = b * Nn + k0 + nl;
            As[v * LDV + nl] = (short)f2bf(ew[(size_t)n * Vv + v] * scale[n]);
        }
#pragma unroll
        for (int p = 0; p < 8; p++) {
            int e = tid + 256 * p;
            int h = e & 255, kgrp = e >> 8;
            int kl = kgrp * 4;
            v4s16 tmp;
#pragma unroll
            for (int c = 0; c < 4; c++)
                tmp[c] = (short)g[(size_t)(b * Nn + k0 + kl + c) * Hd + h];
            *(v4s16*)&Bs[h * LDV + kl] = tmp;
        }
        __syncthreads();
        v8s af[4], bfr[4];
#pragma unroll
        for (int i = 0; i < 4; i++)
            af[i] = ld_frag36(&As[(i * 16 + r) * LDV + q * 8]);
#pragma unroll
        for (int j = 0; j < 4; j++)
            bfr[j] = ld_frag36(&Bs[(h0 + j * 16 + r) * LDV + q * 8]);
#pragma unroll
        for (int i = 0; i < 4; i++)
#pragma unroll
            for (int j = 0; j < 4; j++)
                acc[i][j] = __builtin_amdgcn_mfma_f32_16x16x32_bf16(af[i], bfr[j], acc[i][j], 0, 0, 0);
        __syncthreads();
    }
#pragma unroll
    for (int i = 0; i < 4; i++)
#pragma unroll
        for (int j = 0; j < 4; j++) {
            int col = h0 + j * 16 + r;
#pragma unroll
            for (int rg = 0; rg < 4; rg++) {
                int v = i * 16 + q * 4 + rg;
                vn[(size_t)(b * Vv + v) * Hd + col] = f2bf(acc[i][j][rg]);
            }
        }
}

// ---------------- head: gf = mean_v vn2 ; out = relu(gf@mW1+mb1)@mW2+mb2 ------
__global__ __launch_bounds__(256) void k_head(const float* __restrict__ vn2,
                                              const float* __restrict__ mW1,
                                              const float* __restrict__ mb1,
                                              const float* __restrict__ mW2,
                                              const float* __restrict__ mb2,
                                              float* __restrict__ out) {
    __shared__ float gfs[256];
    __shared__ float zs[256];
    int b = blockIdx.x, t = threadIdx.x;
    float s = 0.f;
    for (int v = 0; v < Vv; v++) s += vn2[(size_t)(b * Vv + v) * Hd + t];
    gfs[t] = s * (1.f / (float)Vv);
    __syncthreads();
    float z = mb1[t];
    for (int k = 0; k < Hd; k++) z += gfs[k] * mW1[k * Hd + t];
    zs[t] = fmaxf(z, 0.f);
    __syncthreads();
    if (t < OUTD) {
        float o = mb2[t];
        for (int ch = 0; ch < Hd; ch++) o += zs[ch] * mW2[ch * OUTD + t];
        out[b * OUTD + t] = o;
    }
}

// =======================================================================
extern "C" void kernel_launch(void* const* d_in, const int* in_sizes, int n_in,
                              void* d_out, int out_size, void* d_ws, size_t ws_size,
                              hipStream_t stream) {
    const float* x     = (const float*)d_in[0];
    const int*   esrc  = (const int*)d_in[1];
    const int*   edst  = (const int*)d_in[2];
    const float* W_emb = (const float*)d_in[3];
    const float* b_emb = (const float*)d_in[4];
    const float* W_gcn = (const float*)d_in[5];
    const float* b_gcn = (const float*)d_in[6];
    const float* aW1   = (const float*)d_in[7];
    const float* ab1   = (const float*)d_in[8];
    const float* aW2   = (const float*)d_in[9];
    const float* ab2   = (const float*)d_in[10];
    const float* vW1   = (const float*)d_in[11];
    const float* vb1   = (const float*)d_in[12];
    const float* vW2   = (const float*)d_in[13];
    const float* vb2   = (const float*)d_in[14];
    const float* mW1   = (const float*)d_in[15];
    const float* mb1   = (const float*)d_in[16];
    const float* mW2   = (const float*)d_in[17];
    const float* mb2   = (const float*)d_in[18];
    const float* ew    = (const float*)d_in[19];
    float* out = (float*)d_out;

    char* w = (char*)d_ws;
    auto alloc = [&](size_t bytes) -> void* {
        void* p = (void*)w;
        w += (bytes + 255) & ~(size_t)255;
        return p;
    };
    int*   cnt      = (int*)  alloc(TOTAL_N * 4);
    int*   rowstart = (int*)  alloc((TOTAL_N + 1) * 4);
    int*   cursor   = (int*)  alloc(TOTAL_N * 4);
    float* dinv     = (float*)alloc(TOTAL_N * 4);
    int2*  csr      = (int2*) alloc((size_t)NE * 8);
    u16*   xa_bf    = (u16*)  alloc((size_t)TOTAL_N * IND * 2);
    float* srow     = (float*)alloc(TOTAL_N * 4);
    u16*   g_bf     = (u16*)  alloc((size_t)TOTAL_N * Hd * 2);
    u16*   t1_bf    = (u16*)  alloc((size_t)TOTAL_N * Hd * 2);
    u16*   t_bf     = (u16*)  alloc((size_t)TOTAL_N * Hd * 2);
    u16*   vn_bf    = (u16*)  alloc((size_t)Bg * Vv * Hd * 2);
    u16*   vtmp_bf  = (u16*)  alloc((size_t)Bg * Vv * Hd * 2);
    float* vn2      = (float*)alloc((size_t)Bg * Vv * Hd * 4);
    float* scale    = (float*)alloc(TOTAL_N * 4);
    float* b12      = (float*)alloc(Hd * 4);
    u16*   wt_a1    = (u16*)  alloc((size_t)Hd * Hd * 2);
    u16*   wt_a2    = (u16*)  alloc((size_t)Hd * Hd * 2);
    u16*   wt_v1    = (u16*)  alloc((size_t)Hd * Hd * 2);
    u16*   wt_v2    = (u16*)  alloc((size_t)Hd * Hd * 2);
    u16*   wt_12    = (u16*)  alloc((size_t)Hd * IND * 2);

    // ---- prep: weight transposes + b12 + zero cnt + wt12 ----
    WtArgs wa;
    wa.src[0] = aW1; wa.dst[0] = wt_a1;
    wa.src[1] = aW2; wa.dst[1] = wt_a2;
    wa.src[2] = vW1; wa.dst[2] = wt_v1;
    wa.src[3] = vW2; wa.dst[3] = wt_v2;
    wa.W_emb = W_emb; wa.b_emb = b_emb; wa.W_gcn = W_gcn;
    wa.b12 = b12; wa.cnt = cnt; wa.wt12 = wt_12;
    k_prep<<<225, 256, 0, stream>>>(wa);

    // ---- CSR build ----
    k_count<<<NE / 256, 256, 0, stream>>>(edst, cnt);
    k_scan<<<1, 1024, 0, stream>>>(cnt, rowstart, cursor, dinv);
    k_scatter<<<NE / 256, 256, 0, stream>>>(esrc, edst, cursor, dinv, csr);

    // ---- xa = A_norm@x + x/deg (bf16) ; srow ----
    k_aggx<<<TOTAL_N / 4, 256, 0, stream>>>((const float2*)x, rowstart, csr, dinv,
                                            xa_bf, srow);

    // ---- g = relu(xa@W12 + srow*b12 + b_gcn) ----
    k_mfma_gemm<u16, u16><<<dim3(2, TOTAL_N / 128), 256, 0, stream>>>(
        xa_bf, wt_12, b_gcn, srow, b12, g_bf, TOTAL_N, IND, 1);

    // ---- t = relu(g@aW1+ab1)@aW2+ab2 ----
    k_mfma_gemm<u16, u16><<<dim3(2, TOTAL_N / 128), 256, 0, stream>>>(
        g_bf, wt_a1, ab1, nullptr, nullptr, t1_bf, TOTAL_N, Hd, 1);
    k_mfma_gemm<u16, u16><<<dim3(2, TOTAL_N / 128), 256, 0, stream>>>(
        t1_bf, wt_a2, ab2, nullptr, nullptr, t_bf, TOTAL_N, Hd, 0);

    // ---- fused proto + att scale ----
    k_proto_att<<<Bg, 1024, 0, stream>>>(t_bf, ew, scale);

    // ---- vn = (ew*scale)^T @ g per graph (MFMA) ----
    k_vn_mfma<<<Bg, 256, 0, stream>>>(ew, scale, g_bf, vn_bf);

    // ---- vn MLP ----
    k_mfma_gemm<u16, u16><<<dim3(2, (Bg * Vv) / 128), 256, 0, stream>>>(
        vn_bf, wt_v1, vb1, nullptr, nullptr, vtmp_bf, Bg * Vv, Hd, 1);
    k_mfma_gemm<u16, float><<<dim3(2, (Bg * Vv) / 128), 256, 0, stream>>>(
        vtmp_bf, wt_v2, vb2, nullptr, nullptr, vn2, Bg * Vv, Hd, 0);

    // ---- head ----
    k_head<<<Bg, 256, 0, stream>>>(vn2, mW1, mb1, mW2, mb2, out);
}